// Round 5
// baseline (270.344 us; speedup 1.0000x reference)
//
#include <hip/hip_runtime.h>
#include <hip/hip_bf16.h>
#include <cstdint>

typedef unsigned short u16;
typedef short v8s __attribute__((ext_vector_type(8)));   // 8 bf16 (4 VGPRs) MFMA A/B frag
typedef float v4f __attribute__((ext_vector_type(4)));   // MFMA C/D frag
typedef u16 u16x8 __attribute__((ext_vector_type(8)));
typedef u16 u16x4 __attribute__((ext_vector_type(4)));

static constexpr int Bb = 8, Cc = 512, Ll = 2048, Hh = 8, Dh = 64;

__device__ __forceinline__ float bf2f(u16 u){
  unsigned x = ((unsigned)u) << 16; float f; __builtin_memcpy(&f, &x, 4); return f;
}
__device__ __forceinline__ u16 f2bf(float f){
  unsigned x; __builtin_memcpy(&x, &f, 4);
  x = (x + 0x7fffu + ((x >> 16) & 1u)) >> 16; return (u16)x;  // RNE
}

__device__ __forceinline__ void async_cp16(const u16* g, u16* l){
  __builtin_amdgcn_global_load_lds(
      (const __attribute__((address_space(1))) unsigned int*)g,
      (__attribute__((address_space(3))) unsigned int*)l, 16, 0, 0);
}

#if __has_builtin(__builtin_amdgcn_exp2f)
#define EXP2F(x) __builtin_amdgcn_exp2f(x)
#else
#define EXP2F(x) exp2f(x)
#endif

// ---------------- dtype detector (flag: 1 = fp32 inputs)
__global__ __launch_bounds__(256) void detect_dtype(const u16* __restrict__ x, unsigned* __restrict__ flag){
  __shared__ int cnt;
  if (threadIdx.x == 0) cnt = 0;
  __syncthreads();
  int sane = 0;
  for (int i = threadIdx.x; i < 4096; i += 256){
    unsigned e = (x[2 * i] >> 7) & 0xFFu;
    sane += (e >= 90u && e <= 160u) ? 1 : 0;
  }
  atomicAdd(&cnt, sane);
  __syncthreads();
  if (threadIdx.x == 0) *flag = (cnt < 2458) ? 1u : 0u;
}

// ---------------- transpose + pad (zeroes boundary rows itself; no memset needed)
__global__ __launch_bounds__(256) void transpose_pad(const void* __restrict__ xv, const unsigned* __restrict__ flagp,
                                                     u16* __restrict__ xT){
  int b = blockIdx.z, ci0 = blockIdx.y * 64, l0 = blockIdx.x * 64;
  __shared__ u16 tb[64 * 72];             // [l][ci], stride 72 pad
  const unsigned isf32 = *flagp;
  int t = threadIdx.x;
  int row = t >> 3, seg = t & 7;
  if (isf32){
    const float* xf = (const float*)xv;
    #pragma unroll
    for (int rnd = 0; rnd < 2; rnd++){
      int ci = row + rnd * 32;
      size_t off = ((size_t)(b * Cc + ci0 + ci)) * Ll + l0 + seg * 8;
      v4f a = *(const v4f*)(xf + off);
      v4f c4 = *(const v4f*)(xf + off + 4);
      #pragma unroll
      for (int j = 0; j < 4; j++) tb[(seg * 8 + j) * 72 + ci] = f2bf(a[j]);
      #pragma unroll
      for (int j = 0; j < 4; j++) tb[(seg * 8 + 4 + j) * 72 + ci] = f2bf(c4[j]);
    }
  } else {
    const u16* x = (const u16*)xv;
    #pragma unroll
    for (int rnd = 0; rnd < 2; rnd++){
      int ci = row + rnd * 32;
      u16x8 v = *(const u16x8*)(x + ((size_t)(b * Cc + ci0 + ci)) * Ll + l0 + seg * 8);
      #pragma unroll
      for (int j = 0; j < 8; j++) tb[(seg * 8 + j) * 72 + ci] = v[j];
    }
  }
  __syncthreads();
  #pragma unroll
  for (int rnd = 0; rnd < 2; rnd++){
    int l = row + rnd * 32;
    u16x8 v = *(const u16x8*)&tb[l * 72 + seg * 8];
    *(u16x8*)(xT + ((size_t)b * 2050 + 1 + l0 + l) * Cc + ci0 + seg * 8) = v;
  }
  // zero pad rows 0 / 2049
  if (blockIdx.x == 0 && t < 8){
    u16x8 z = {};
    *(u16x8*)(xT + ((size_t)b * 2050 + 0) * Cc + ci0 + t * 8) = z;
  }
  if (blockIdx.x == 31 && t < 8){
    u16x8 z = {};
    *(u16x8*)(xT + ((size_t)b * 2050 + 2049) * Cc + ci0 + t * 8) = z;
  }
}

// ---------------- weight + bias repack: wp[((conv*3+k)*512+co)*512+ci] = w_conv[co][ci][k]; bb appended
__global__ __launch_bounds__(256) void pack_wb(const void* __restrict__ w0, const void* __restrict__ w1,
                                               const void* __restrict__ w2, const void* __restrict__ b0,
                                               const void* __restrict__ b1, const void* __restrict__ b2,
                                               const unsigned* __restrict__ flagp,
                                               u16* __restrict__ wp, u16* __restrict__ bb){
  int g = blockIdx.x * 256 + threadIdx.x;
  const unsigned isf32 = *flagp;
  if (g < 9 * 512 * 512){
    int ci = g & 511, co = (g >> 9) & 511, kc = g >> 18;   // kc = conv*3+k
    int conv = kc / 3, k = kc - conv * 3;
    const void* w = (conv == 0) ? w0 : ((conv == 1) ? w1 : w2);
    size_t idx = (size_t)co * 1536 + ci * 3 + k;
    wp[g] = isf32 ? f2bf(((const float*)w)[idx]) : ((const u16*)w)[idx];
  } else {
    int g2 = g - 9 * 512 * 512;
    if (g2 < 1536){
      int conv = g2 >> 9, c = g2 & 511;
      const void* bsrc = (conv == 0) ? b0 : ((conv == 1) ? b1 : b2);
      bb[g2] = isf32 ? f2bf(((const float*)bsrc)[c]) : ((const u16*)bsrc)[c];
    }
  }
}

// ---------------- fused conv GEMM, depth-1 double-buffer, ONE barrier per K-tile.
// 128M x 256N tile, BK=64, 768 blocks = EXACTLY 3 full rounds of 256 CUs (no grid tail).
// 8 waves (2M x 4N), per-wave 64x64 output, 96 KiB LDS (2 bufs x (A 128x64 + B 256x64)).
// Per kt: stage kt+1 into buf^1 (6 DMAs/thread), snake MFMA columns (LOAD_A once, then
// per-n LOAD_B + 8 MFMA), vmcnt(0)+one barrier at end. LDS swizzle: byte ^= (row&7)<<4
// (G4 formula; measured 0 bank conflicts). Source pre-swizzled, gload_lds dests linear.
__global__ __launch_bounds__(512, 2) void conv_gemm_fused(const u16* __restrict__ wp, const u16* __restrict__ xT,
                                                          const u16* __restrict__ bb, u16* __restrict__ qT,
                                                          u16* __restrict__ kT, u16* __restrict__ vN){
  __shared__ u16 smem[49152];   // 96 KiB: 2 bufs x 24576 elems (A 8192 + B 16384)
  int bx = blockIdx.x;
  int b = bx & 7, inner = bx >> 3;            // b -> XCD (one batch per XCD L2)
  int mt = inner >> 3, nt = inner & 7;        // mt 0..11, nt 0..7
  int m0 = mt << 7, n0 = nt << 8;
  int conv = m0 >> 9, co0 = m0 & 511;

  int t = threadIdx.x, wave = t >> 6, lane = t & 63, quad = lane >> 4, lid = lane & 15;
  int wm_i = wave >> 2, wn_i = wave & 3;      // 2M x 4N

  // read-side swizzle: byte-col ^= (row&7)<<4; all frag rows have row%8 == lid%8
  int sx = (lid & 7) << 4;                               // byte XOR
  int cb0 = ((quad * 16) ^ sx) >> 1;                     // elem col, kh=0
  int cb1 = ((64 + quad * 16) ^ sx) >> 1;                // elem col, kh=1
  int abase0 = (wm_i * 64 + lid) * 64;                   // elem, A region (128 rows)
  int bbase0 = 8192 + (wn_i * 64 + lid) * 64;            // elem, B region (256 rows)

  // staging maps: LDS linear byte p (row=p>>7, cb=p&127) <- global col cb ^ ((row&7)<<4)
  int srcA[2], srcB[4];
  #pragma unroll
  for (int r = 0; r < 2; r++){
    int p = t * 16 + r * 8192;                 // byte into 16 KiB A region
    int row = p >> 7, c = (p & 127) ^ ((row & 7) << 4);
    srcA[r] = row * 512 + (c >> 1);
  }
  #pragma unroll
  for (int r = 0; r < 4; r++){
    int p = t * 16 + r * 8192;                 // byte into 32 KiB B region
    int row = p >> 7, c = (p & 127) ^ ((row & 7) << 4);
    srcB[r] = row * 512 + (c >> 1);
  }
  int dA0 = t * 8, dA1 = t * 8 + 4096;
  // B dests: 8192 + t*8 + r*4096

  const u16* aGbase = wp + (size_t)(conv * 1536 + co0) * 512;
  const u16* bGbase = xT + (size_t)b * (2050 * 512) + (size_t)n0 * 512;

#define STAGE_TILE(aG, bG, stg) do{ \
    async_cp16((aG) + srcA[0], (stg) + dA0); \
    async_cp16((aG) + srcA[1], (stg) + dA1); \
    _Pragma("unroll") for (int r = 0; r < 4; ++r) \
      async_cp16((bG) + srcB[r], (stg) + 8192 + t * 8 + r * 4096); }while(0)

#define LOAD_A() do{ \
    _Pragma("unroll") for (int m = 0; m < 4; ++m){ \
      af[m][0] = *(const v8s*)(lds + abase0 + m * 1024 + cb0); \
      af[m][1] = *(const v8s*)(lds + abase0 + m * 1024 + cb1); } }while(0)

#define LOAD_Bn(n) do{ \
    bfc[0] = *(const v8s*)(lds + bbase0 + (n) * 1024 + cb0); \
    bfc[1] = *(const v8s*)(lds + bbase0 + (n) * 1024 + cb1); }while(0)

#define MFMA_COL(n) do{ \
    __builtin_amdgcn_s_setprio(1); \
    _Pragma("unroll") for (int m = 0; m < 4; ++m) \
    _Pragma("unroll") for (int kh = 0; kh < 2; ++kh) \
      acc[m][n] = __builtin_amdgcn_mfma_f32_16x16x32_bf16(af[m][kh], bfc[kh], acc[m][n], 0, 0, 0); \
    __builtin_amdgcn_s_setprio(0); }while(0)

  v4f acc[4][4] = {};   // [m][n]
  v8s af[4][2], bfc[2];

  // ---- prologue: stage kt=0 into buf0, drain, barrier
  STAGE_TILE(aGbase, bGbase, smem);
  asm volatile("s_waitcnt vmcnt(0)" ::: "memory");
  __builtin_amdgcn_sched_barrier(0);
  __builtin_amdgcn_s_barrier();

  // ---- main loop: 24 K-tiles (3 taps x 8 ci-steps)
  #pragma unroll 2
  for (int kt = 0; kt < 24; ++kt){
    u16* lds = smem + (kt & 1) * 24576;
    u16* stg = smem + ((kt + 1) & 1) * 24576;
    // issue kt+1 stages first (full tile of compute to hide HBM/L2 latency)
    if (kt < 23){
      int k1 = kt + 1;
      int ks1 = k1 >> 3, ci1 = (k1 & 7) << 6;
      const u16* aG = aGbase + (size_t)ks1 * 262144 + ci1;
      const u16* bG = bGbase + (size_t)ks1 * 512 + ci1;
      STAGE_TILE(aG, bG, stg);
    }
    // snake columns, no intra-tile barriers
    LOAD_A();
    LOAD_Bn(0); MFMA_COL(0);
    LOAD_Bn(1); MFMA_COL(1);
    LOAD_Bn(2); MFMA_COL(2);
    LOAD_Bn(3); MFMA_COL(3);
    if (kt < 23){
      asm volatile("s_waitcnt vmcnt(0)" ::: "memory");
      __builtin_amdgcn_sched_barrier(0);
      __builtin_amdgcn_s_barrier();
    }
  }

#undef STAGE_TILE
#undef LOAD_A
#undef LOAD_Bn
#undef MFMA_COL

  // ---- epilogue
  const float qsc = (float)(1.4426950408889634 / 22.627416997969522);
  if (conv < 2){
    u16* dst = (conv == 0) ? qT : kT;
    #pragma unroll
    for (int m = 0; m < 4; ++m){
      int cog = m0 + wm_i * 64 + m * 16 + quad * 4;
      float bv[4];
      #pragma unroll
      for (int r = 0; r < 4; r++) bv[r] = bf2f(bb[cog + r]);
      int coc = cog & 511;
      #pragma unroll
      for (int n = 0; n < 4; ++n){
        int l = n0 + wn_i * 64 + n * 16 + lid;
        u16x4 pk;
        #pragma unroll
        for (int r = 0; r < 4; r++){
          float v = acc[m][n][r] + bv[r];
          if (conv == 0) v *= qsc;
          pk[r] = f2bf(v);
        }
        *(u16x4*)(dst + ((((size_t)b * Hh + (coc >> 6)) * Ll + l) << 6) + (coc & 63)) = pk;
      }
    }
  } else {
    // v: LDS-bounce transpose -> vectorized [b][co][l] stores. scr = [128 co][264]
    u16* scr = smem;
    __syncthreads();
    #pragma unroll
    for (int m = 0; m < 4; ++m){
      int rloc = wm_i * 64 + m * 16 + quad * 4;
      int cog = m0 + rloc;
      float bv[4];
      #pragma unroll
      for (int r = 0; r < 4; r++) bv[r] = bf2f(bb[cog + r]);
      #pragma unroll
      for (int n = 0; n < 4; ++n){
        int lcl = wn_i * 64 + n * 16 + lid;
        #pragma unroll
        for (int r = 0; r < 4; r++)
          scr[(rloc + r) * 264 + lcl] = f2bf(acc[m][n][r] + bv[r]);
      }
    }
    __syncthreads();
    int seg = t & 31, rw = t >> 5;        // seg 0..31 (8-elem cols), rw 0..15
    #pragma unroll
    for (int ps = 0; ps < 8; ++ps){
      int row = rw + ps * 16;
      u16x8 vv = *(const u16x8*)&scr[row * 264 + seg * 8];
      *(u16x8*)(vN + (((size_t)b * Cc + co0 + row) << 11) + n0 + seg * 8) = vv;
    }
  }
}

// ---------------- flash attention: fixed-max softmax, permuted-slot K, fully-async staging,
// lsum via ones-MFMA. Grid (bh=64, ltile=16) for XCD L2 locality.
__global__ __launch_bounds__(256) void attn_kernel(const u16* __restrict__ qT, const u16* __restrict__ kT,
                                                   const u16* __restrict__ vN, const unsigned* __restrict__ flagp,
                                                   void* __restrict__ outv){
  int bhx = blockIdx.x;                 // 0..63
  int b = bhx >> 3, h = bhx & 7, l0 = blockIdx.y * 128;
  int t = threadIdx.x, w = t >> 6, lane = t & 63, quad = lane >> 4, lid = lane & 15;
  __shared__ u16 kls[128 * 72];    // K tile [slot][d], stride 72 (pad cols 64..71)
  __shared__ u16 vls[64 * 136];    // V tile [d][m], stride 136 (pad cols 128..135)
  const unsigned isf32 = *flagp;
  const size_t bh = (size_t)b * Hh + h;

  // per-lane async staging maps (loop-invariant). Window e=(r*256+t)*8 elems into padded LDS;
  // windows landing in pad load a clamped dummy (pad bytes never read).
  int kadd[5], vadd[5];
  bool kval[5], vval[5];
  #pragma unroll
  for (int r = 0; r < 5; r++){
    int e = (r * 256 + t) * 8;
    kval[r] = e < 128 * 72;
    int slot = e / 72, off = e - slot * 72;
    int s5 = slot & 31;
    int m = (slot & ~31) | (((s5 >> 2) & 1) << 3) | (((s5 >> 3) & 1) << 4) | (((s5 >> 4) & 1) << 2) | (s5 & 3);
    kadd[r] = m * 64 + (off < 64 ? off : 0);
    vval[r] = e < 64 * 136;
    int d = e / 136, voff = e - d * 136;
    vadd[r] = d * Ll + (voff < 128 ? voff : 0);
  }
  const u16* kTb = kT + bh * Ll * 64;
  const u16* vNb = vN + ((size_t)(b * Cc + h * Dh)) * Ll;

  // Q fragments in registers (B-operand of S^T GEMM)
  v8s qF[2][2];
  #pragma unroll
  for (int ci = 0; ci < 2; ci++)
    #pragma unroll
    for (int ks = 0; ks < 2; ks++)
      qF[ci][ks] = *(const v8s*)(qT + ((bh * Ll) + l0 + w * 32 + ci * 16 + lid) * 64 + ks * 32 + quad * 8);

  const v8s onesF = {0x3F80, 0x3F80, 0x3F80, 0x3F80, 0x3F80, 0x3F80, 0x3F80, 0x3F80};
  v4f o[2][4] = {};                // [ci][df]
  v4f o1[2] = {};                  // lsum accumulators (all cols equal)

  for (int mt = 0; mt < 16; mt++){
    int m0 = mt * 128;
    const u16* kt = kTb + (size_t)m0 * 64;
    const u16* vt = vNb + m0;
    #pragma unroll
    for (int r = 0; r < 5; r++)
      if (kval[r]) async_cp16(kt + kadd[r], &kls[(r * 256 + t) * 8]);
    #pragma unroll
    for (int r = 0; r < 5; r++)
      if (vval[r]) async_cp16(vt + vadd[r], &vls[(r * 256 + t) * 8]);
    __syncthreads();

    // S^T: s[c][tt][ci] reg r = S^T[m0 + c*32 + quad*8 + tt*4 + r][w*32+ci*16+lid]
    v4f s[4][2][2] = {};
    #pragma unroll
    for (int ks = 0; ks < 2; ks++){
      v8s aF[4][2];
      #pragma unroll
      for (int c = 0; c < 4; c++)
        #pragma unroll
        for (int tt = 0; tt < 2; tt++)
          aF[c][tt] = *(const v8s*)&kls[(c * 32 + tt * 16 + lid) * 72 + ks * 32 + quad * 8];
      #pragma unroll
      for (int c = 0; c < 4; c++)
        #pragma unroll
        for (int tt = 0; tt < 2; tt++){
          s[c][tt][0] = __builtin_amdgcn_mfma_f32_16x16x32_bf16(aF[c][tt], qF[0][ks], s[c][tt][0], 0, 0, 0);
          s[c][tt][1] = __builtin_amdgcn_mfma_f32_16x16x32_bf16(aF[c][tt], qF[1][ks], s[c][tt][1], 0, 0, 0);
        }
    }

    // fixed-max softmax: p = exp2(s) packed straight into PV A-frags; lsum via ones-MFMA
    #pragma unroll
    for (int c = 0; c < 4; c++){
      v8s aP[2];
      #pragma unroll
      for (int ci = 0; ci < 2; ci++){
        float p[8];
        #pragma unroll
        for (int tt = 0; tt < 2; tt++)
          #pragma unroll
          for (int r = 0; r < 4; r++)
            p[tt * 4 + r] = EXP2F(s[c][tt][ci][r]);
        unsigned u[4];
        #pragma unroll
        for (int k2 = 0; k2 < 4; k2++){
          __hip_bfloat162 hb = __float22bfloat162_rn(make_float2(p[2 * k2], p[2 * k2 + 1]));
          __builtin_memcpy(&u[k2], &hb, 4);
        }
        __builtin_memcpy(&aP[ci], u, 16);
      }
      v8s bV[4];
      #pragma unroll
      for (int df = 0; df < 4; df++)
        bV[df] = *(const v8s*)&vls[(df * 16 + lid) * 136 + c * 32 + quad * 8];
      #pragma unroll
      for (int ci = 0; ci < 2; ci++){
        #pragma unroll
        for (int df = 0; df < 4; df++)
          o[ci][df] = __builtin_amdgcn_mfma_f32_16x16x32_bf16(aP[ci], bV[df], o[ci][df], 0, 0, 0);
        o1[ci] = __builtin_amdgcn_mfma_f32_16x16x32_bf16(aP[ci], onesF, o1[ci], 0, 0, 0);
      }
    }
    __syncthreads();
  }

  #pragma unroll
  for (int lf = 0; lf < 2; lf++){
    v4f nv;
    #pragma unroll
    for (int r = 0; r < 4; r++) nv[r] = 1.f / o1[lf][r];
    #pragma unroll
    for (int df = 0; df < 4; df++){
      int d = df * 16 + lid;
      int l = l0 + w * 32 + lf * 16 + quad * 4;
      size_t ofs = (((bh << 6) + d) << 11) + l;
      if (isf32){
        v4f st;
        #pragma unroll
        for (int r = 0; r < 4; r++) st[r] = o[lf][df][r] * nv[r];
        *(v4f*)((float*)outv + ofs) = st;
      } else {
        u16x4 pk;
        #pragma unroll
        for (int r = 0; r < 4; r++) pk[r] = f2bf(o[lf][df][r] * nv[r]);
        *(u16x4*)((u16*)outv + ofs) = pk;
      }
    }
  }
}

extern "C" void kernel_launch(void* const* d_in, const int* in_sizes, int n_in,
                              void* d_out, int out_size, void* d_ws, size_t ws_size,
                              hipStream_t stream){
  const void* x  = d_in[0];
  const void* w0 = d_in[1];
  const void* b0 = d_in[2];
  const void* w1 = d_in[3];
  const void* b1 = d_in[4];
  const void* w2 = d_in[5];
  const void* b2 = d_in[6];
  u16* ws = (u16*)d_ws;
  unsigned* flag = (unsigned*)ws;                // 1 u32 at base (64 u16 slot, aligned)
  u16* xT = ws + 64;                             // [8][2050][512]
  u16* wp = xT + (size_t)8 * 2050 * 512;         // [9][512][512]
  u16* bb = wp + (size_t)9 * 512 * 512;          // [3][512]
  u16* qT = bb + 1536;                           // [8][8][2048][64]
  u16* kT = qT + (size_t)8 * 8 * 2048 * 64;
  u16* vN = kT + (size_t)8 * 8 * 2048 * 64;      // [8][512][2048]

  detect_dtype<<<1, 256, 0, stream>>>((const u16*)x, flag);
  transpose_pad<<<dim3(32, 8, 8), 256, 0, stream>>>(x, flag, xT);
  pack_wb<<<dim3(9 * 512 * 512 / 256 + 6), 256, 0, stream>>>(w0, w1, w2, b0, b1, b2, flag, wp, bb);
  conv_gemm_fused<<<dim3(768), 512, 0, stream>>>(wp, xT, bb, qT, kT, vN);
  attn_kernel<<<dim3(64, 16), 256, 0, stream>>>(qT, kT, vN, flag, d_out);
}

// Round 6
// 263.067 us; speedup vs baseline: 1.0277x; 1.0277x over previous
//
#include <hip/hip_runtime.h>
#include <hip/hip_bf16.h>
#include <cstdint>

typedef unsigned short u16;
typedef short v8s __attribute__((ext_vector_type(8)));   // 8 bf16 (4 VGPRs) MFMA A/B frag
typedef float v4f __attribute__((ext_vector_type(4)));   // MFMA C/D frag
typedef u16 u16x8 __attribute__((ext_vector_type(8)));
typedef u16 u16x4 __attribute__((ext_vector_type(4)));

static constexpr int Bb = 8, Cc = 512, Ll = 2048, Hh = 8, Dh = 64;

__device__ __forceinline__ float bf2f(u16 u){
  unsigned x = ((unsigned)u) << 16; float f; __builtin_memcpy(&f, &x, 4); return f;
}
__device__ __forceinline__ u16 f2bf(float f){
  unsigned x; __builtin_memcpy(&x, &f, 4);
  x = (x + 0x7fffu + ((x >> 16) & 1u)) >> 16; return (u16)x;  // RNE
}

__device__ __forceinline__ void async_cp16(const u16* g, u16* l){
  __builtin_amdgcn_global_load_lds(
      (const __attribute__((address_space(1))) unsigned int*)g,
      (__attribute__((address_space(3))) unsigned int*)l, 16, 0, 0);
}

#if __has_builtin(__builtin_amdgcn_exp2f)
#define EXP2F(x) __builtin_amdgcn_exp2f(x)
#else
#define EXP2F(x) exp2f(x)
#endif

// ---------------- dtype detector (flag: 1 = fp32 inputs)
__global__ __launch_bounds__(256) void detect_dtype(const u16* __restrict__ x, unsigned* __restrict__ flag){
  __shared__ int cnt;
  if (threadIdx.x == 0) cnt = 0;
  __syncthreads();
  int sane = 0;
  for (int i = threadIdx.x; i < 4096; i += 256){
    unsigned e = (x[2 * i] >> 7) & 0xFFu;
    sane += (e >= 90u && e <= 160u) ? 1 : 0;
  }
  atomicAdd(&cnt, sane);
  __syncthreads();
  if (threadIdx.x == 0) *flag = (cnt < 2458) ? 1u : 0u;
}

// ---------------- transpose + pad (zeroes boundary rows itself; no memset needed)
__global__ __launch_bounds__(256) void transpose_pad(const void* __restrict__ xv, const unsigned* __restrict__ flagp,
                                                     u16* __restrict__ xT){
  int b = blockIdx.z, ci0 = blockIdx.y * 64, l0 = blockIdx.x * 64;
  __shared__ u16 tb[64 * 72];             // [l][ci], stride 72 pad
  const unsigned isf32 = *flagp;
  int t = threadIdx.x;
  int row = t >> 3, seg = t & 7;
  if (isf32){
    const float* xf = (const float*)xv;
    #pragma unroll
    for (int rnd = 0; rnd < 2; rnd++){
      int ci = row + rnd * 32;
      size_t off = ((size_t)(b * Cc + ci0 + ci)) * Ll + l0 + seg * 8;
      v4f a = *(const v4f*)(xf + off);
      v4f c4 = *(const v4f*)(xf + off + 4);
      #pragma unroll
      for (int j = 0; j < 4; j++) tb[(seg * 8 + j) * 72 + ci] = f2bf(a[j]);
      #pragma unroll
      for (int j = 0; j < 4; j++) tb[(seg * 8 + 4 + j) * 72 + ci] = f2bf(c4[j]);
    }
  } else {
    const u16* x = (const u16*)xv;
    #pragma unroll
    for (int rnd = 0; rnd < 2; rnd++){
      int ci = row + rnd * 32;
      u16x8 v = *(const u16x8*)(x + ((size_t)(b * Cc + ci0 + ci)) * Ll + l0 + seg * 8);
      #pragma unroll
      for (int j = 0; j < 8; j++) tb[(seg * 8 + j) * 72 + ci] = v[j];
    }
  }
  __syncthreads();
  #pragma unroll
  for (int rnd = 0; rnd < 2; rnd++){
    int l = row + rnd * 32;
    u16x8 v = *(const u16x8*)&tb[l * 72 + seg * 8];
    *(u16x8*)(xT + ((size_t)b * 2050 + 1 + l0 + l) * Cc + ci0 + seg * 8) = v;
  }
  // zero pad rows 0 / 2049
  if (blockIdx.x == 0 && t < 8){
    u16x8 z = {};
    *(u16x8*)(xT + ((size_t)b * 2050 + 0) * Cc + ci0 + t * 8) = z;
  }
  if (blockIdx.x == 31 && t < 8){
    u16x8 z = {};
    *(u16x8*)(xT + ((size_t)b * 2050 + 2049) * Cc + ci0 + t * 8) = z;
  }
}

// ---------------- weight + bias repack: wp[((conv*3+k)*512+co)*512+ci] = w_conv[co][ci][k]; bb appended
__global__ __launch_bounds__(256) void pack_wb(const void* __restrict__ w0, const void* __restrict__ w1,
                                               const void* __restrict__ w2, const void* __restrict__ b0,
                                               const void* __restrict__ b1, const void* __restrict__ b2,
                                               const unsigned* __restrict__ flagp,
                                               u16* __restrict__ wp, u16* __restrict__ bb){
  int g = blockIdx.x * 256 + threadIdx.x;
  const unsigned isf32 = *flagp;
  if (g < 9 * 512 * 512){
    int ci = g & 511, co = (g >> 9) & 511, kc = g >> 18;   // kc = conv*3+k
    int conv = kc / 3, k = kc - conv * 3;
    const void* w = (conv == 0) ? w0 : ((conv == 1) ? w1 : w2);
    size_t idx = (size_t)co * 1536 + ci * 3 + k;
    wp[g] = isf32 ? f2bf(((const float*)w)[idx]) : ((const u16*)w)[idx];
  } else {
    int g2 = g - 9 * 512 * 512;
    if (g2 < 1536){
      int conv = g2 >> 9, c = g2 & 511;
      const void* bsrc = (conv == 0) ? b0 : ((conv == 1) ? b1 : b2);
      bb[g2] = isf32 ? f2bf(((const float*)bsrc)[c]) : ((const u16*)bsrc)[c];
    }
  }
}

// ---------------- fused conv GEMM, depth-2 triple-buffer with COUNTED vmcnt (T4).
// 128M x 256N tile, BK=64, 768 blocks = 3 full rounds of 256 CUs. 8 waves (2M x 4N),
// per-wave 64x64 output, 144 KiB LDS (3 bufs x (A 128x64 + B 256x64)).
// Per kt: stage kt+2 into buf[(kt+2)%3], compute buf[kt%3], then vmcnt(6) (certifies
// own-wave kt+1 DMAs; kt+2's 6 stay in flight across the barrier — never drain to 0).
// LDS swizzle: byte ^= (row&7)<<4 (measured 0 bank conflicts); source pre-swizzled.
__global__ __launch_bounds__(512, 2) void conv_gemm_fused(const u16* __restrict__ wp, const u16* __restrict__ xT,
                                                          const u16* __restrict__ bb, u16* __restrict__ qT,
                                                          u16* __restrict__ kT, u16* __restrict__ vN){
  __shared__ u16 smem[73728];   // 144 KiB: 3 bufs x 24576 elems (A 8192 + B 16384)
  int bx = blockIdx.x;
  int b = bx & 7, inner = bx >> 3;            // b -> XCD (one batch per XCD L2)
  int mt = inner >> 3, nt = inner & 7;        // mt 0..11, nt 0..7
  int m0 = mt << 7, n0 = nt << 8;
  int conv = m0 >> 9, co0 = m0 & 511;

  int t = threadIdx.x, wave = t >> 6, lane = t & 63, quad = lane >> 4, lid = lane & 15;
  int wm_i = wave >> 2, wn_i = wave & 3;      // 2M x 4N

  // read-side swizzle: byte-col ^= (row&7)<<4; all frag rows have row%8 == lid%8
  int sx = (lid & 7) << 4;                               // byte XOR
  int cb0 = ((quad * 16) ^ sx) >> 1;                     // elem col, kh=0
  int cb1 = ((64 + quad * 16) ^ sx) >> 1;                // elem col, kh=1
  int abase0 = (wm_i * 64 + lid) * 64;                   // elem, A region (128 rows)
  int bbase0 = 8192 + (wn_i * 64 + lid) * 64;            // elem, B region (256 rows)

  // staging maps: LDS linear byte p (row=p>>7, cb=p&127) <- global col cb ^ ((row&7)<<4)
  int srcA[2], srcB[4];
  #pragma unroll
  for (int r = 0; r < 2; r++){
    int p = t * 16 + r * 8192;                 // byte into 16 KiB A region
    int row = p >> 7, c = (p & 127) ^ ((row & 7) << 4);
    srcA[r] = row * 512 + (c >> 1);
  }
  #pragma unroll
  for (int r = 0; r < 4; r++){
    int p = t * 16 + r * 8192;                 // byte into 32 KiB B region
    int row = p >> 7, c = (p & 127) ^ ((row & 7) << 4);
    srcB[r] = row * 512 + (c >> 1);
  }
  int dA0 = t * 8, dA1 = t * 8 + 4096;
  // B dests: 8192 + t*8 + r*4096

  const u16* aGbase = wp + (size_t)(conv * 1536 + co0) * 512;
  const u16* bGbase = xT + (size_t)b * (2050 * 512) + (size_t)n0 * 512;

#define STAGE_TILE(aG, bG, stg) do{ \
    async_cp16((aG) + srcA[0], (stg) + dA0); \
    async_cp16((aG) + srcA[1], (stg) + dA1); \
    _Pragma("unroll") for (int r = 0; r < 4; ++r) \
      async_cp16((bG) + srcB[r], (stg) + 8192 + t * 8 + r * 4096); }while(0)

#define LOAD_A() do{ \
    _Pragma("unroll") for (int m = 0; m < 4; ++m){ \
      af[m][0] = *(const v8s*)(lds + abase0 + m * 1024 + cb0); \
      af[m][1] = *(const v8s*)(lds + abase0 + m * 1024 + cb1); } }while(0)

#define LOAD_Bn(n) do{ \
    bfc[0] = *(const v8s*)(lds + bbase0 + (n) * 1024 + cb0); \
    bfc[1] = *(const v8s*)(lds + bbase0 + (n) * 1024 + cb1); }while(0)

#define MFMA_COL(n) do{ \
    __builtin_amdgcn_s_setprio(1); \
    _Pragma("unroll") for (int m = 0; m < 4; ++m) \
    _Pragma("unroll") for (int kh = 0; kh < 2; ++kh) \
      acc[m][n] = __builtin_amdgcn_mfma_f32_16x16x32_bf16(af[m][kh], bfc[kh], acc[m][n], 0, 0, 0); \
    __builtin_amdgcn_s_setprio(0); }while(0)

  v4f acc[4][4] = {};   // [m][n]
  v8s af[4][2], bfc[2];

  // ---- prologue: stage kt=0 (buf0) and kt=1 (buf1); wait oldest 6 -> buf0 resident
  STAGE_TILE(aGbase, bGbase, smem);
  STAGE_TILE(aGbase + 64, bGbase + 64, smem + 24576);
  asm volatile("s_waitcnt vmcnt(6)" ::: "memory");
  __builtin_amdgcn_sched_barrier(0);
  __builtin_amdgcn_s_barrier();

  // ---- main loop: 24 K-tiles (3 taps x 8 ci-steps)
  #pragma unroll 3
  for (int kt = 0; kt < 24; ++kt){
    u16* lds = smem + (kt % 3) * 24576;
    // issue kt+2 stages (two full compute phases to hide HBM/L2 latency)
    if (kt < 22){
      int k2 = kt + 2;
      int ks2 = k2 >> 3, ci2 = (k2 & 7) << 6;
      const u16* aG = aGbase + (size_t)ks2 * 262144 + ci2;
      const u16* bG = bGbase + (size_t)ks2 * 512 + ci2;
      u16* stg = smem + (k2 % 3) * 24576;
      STAGE_TILE(aG, bG, stg);
    }
    // snake columns, no intra-tile barriers
    LOAD_A();
    LOAD_Bn(0); MFMA_COL(0);
    LOAD_Bn(1); MFMA_COL(1);
    LOAD_Bn(2); MFMA_COL(2);
    LOAD_Bn(3); MFMA_COL(3);
    if (kt < 22){
      asm volatile("s_waitcnt vmcnt(6)" ::: "memory");   // kt+1 landed; kt+2 in flight
      __builtin_amdgcn_sched_barrier(0);
      __builtin_amdgcn_s_barrier();
    } else if (kt == 22){
      asm volatile("s_waitcnt vmcnt(0)" ::: "memory");   // final: kt=23 landed
      __builtin_amdgcn_sched_barrier(0);
      __builtin_amdgcn_s_barrier();
    }
  }

#undef STAGE_TILE
#undef LOAD_A
#undef LOAD_Bn
#undef MFMA_COL

  // ---- epilogue
  const float qsc = (float)(1.4426950408889634 / 22.627416997969522);
  if (conv < 2){
    u16* dst = (conv == 0) ? qT : kT;
    #pragma unroll
    for (int m = 0; m < 4; ++m){
      int cog = m0 + wm_i * 64 + m * 16 + quad * 4;
      float bv[4];
      #pragma unroll
      for (int r = 0; r < 4; r++) bv[r] = bf2f(bb[cog + r]);
      int coc = cog & 511;
      #pragma unroll
      for (int n = 0; n < 4; ++n){
        int l = n0 + wn_i * 64 + n * 16 + lid;
        u16x4 pk;
        #pragma unroll
        for (int r = 0; r < 4; r++){
          float v = acc[m][n][r] + bv[r];
          if (conv == 0) v *= qsc;
          pk[r] = f2bf(v);
        }
        *(u16x4*)(dst + ((((size_t)b * Hh + (coc >> 6)) * Ll + l) << 6) + (coc & 63)) = pk;
      }
    }
  } else {
    // v: LDS-bounce transpose -> vectorized [b][co][l] stores. scr = [128 co][264]
    u16* scr = smem;
    __syncthreads();
    #pragma unroll
    for (int m = 0; m < 4; ++m){
      int rloc = wm_i * 64 + m * 16 + quad * 4;
      int cog = m0 + rloc;
      float bv[4];
      #pragma unroll
      for (int r = 0; r < 4; r++) bv[r] = bf2f(bb[cog + r]);
      #pragma unroll
      for (int n = 0; n < 4; ++n){
        int lcl = wn_i * 64 + n * 16 + lid;
        #pragma unroll
        for (int r = 0; r < 4; r++)
          scr[(rloc + r) * 264 + lcl] = f2bf(acc[m][n][r] + bv[r]);
      }
    }
    __syncthreads();
    int seg = t & 31, rw = t >> 5;        // seg 0..31 (8-elem cols), rw 0..15
    #pragma unroll
    for (int ps = 0; ps < 8; ++ps){
      int row = rw + ps * 16;
      u16x8 vv = *(const u16x8*)&scr[row * 264 + seg * 8];
      *(u16x8*)(vN + (((size_t)b * Cc + co0 + row) << 11) + n0 + seg * 8) = vv;
    }
  }
}

// ---------------- flash attention: fixed-max softmax, permuted-slot K, double-buffered
// K/V with counted vmcnt, XOR-swizzled unpadded LDS (conv-verified 0-conflict pattern),
// lsum via ones-MFMA, setprio around MFMA clusters. Grid (bh=64, ltile=16).
__global__ __launch_bounds__(256) void attn_kernel(const u16* __restrict__ qT, const u16* __restrict__ kT,
                                                   const u16* __restrict__ vN, const unsigned* __restrict__ flagp,
                                                   void* __restrict__ outv){
  int bhx = blockIdx.x;                 // 0..63
  int b = bhx >> 3, h = bhx & 7, l0 = blockIdx.y * 128;
  int t = threadIdx.x, w = t >> 6, lane = t & 63, quad = lane >> 4, lid = lane & 15;
  __shared__ u16 kls[2][128 * 64];      // K tile [slot][d], unpadded, XOR-swizzled
  __shared__ u16 vls[2][64 * 128];      // V tile [d][m], unpadded, XOR-swizzled
  const unsigned isf32 = *flagp;
  const size_t bh = (size_t)b * Hh + h;
  const int xk = (lid & 7) << 3;        // read-side elem XOR

  // staging maps (loop-invariant): dest linear e=(r*256+t)*8; source pre-swizzled.
  // K: slot=e>>6 col=e&63; global row = perm(slot); global col = col ^ ((slot&7)<<3).
  // V: d=e>>7 m8=e&127; global col = m8 ^ ((d&7)<<3).
  int kadd[4], vadd[4];
  #pragma unroll
  for (int r = 0; r < 4; r++){
    int e = (r * 256 + t) * 8;
    int slot = e >> 6, col = e & 63;
    int s5 = slot & 31;
    int m = (slot & ~31) | (((s5 >> 2) & 1) << 3) | (((s5 >> 3) & 1) << 4) | (((s5 >> 4) & 1) << 2) | (s5 & 3);
    kadd[r] = m * 64 + (col ^ ((slot & 7) << 3));
    int d = e >> 7, m8 = e & 127;
    vadd[r] = d * Ll + (m8 ^ ((d & 7) << 3));
  }
  const u16* kTb = kT + bh * Ll * 64;
  const u16* vNb = vN + ((size_t)(b * Cc + h * Dh)) * Ll;

#define STAGE_KV(mt1) do{ \
    const u16* kp = kTb + (size_t)(mt1) * 8192; \
    const u16* vp = vNb + (mt1) * 128; \
    u16* kd = &kls[(mt1) & 1][0]; \
    u16* vd = &vls[(mt1) & 1][0]; \
    _Pragma("unroll") for (int r = 0; r < 4; r++) async_cp16(kp + kadd[r], kd + (r * 256 + t) * 8); \
    _Pragma("unroll") for (int r = 0; r < 4; r++) async_cp16(vp + vadd[r], vd + (r * 256 + t) * 8); }while(0)

  // Q fragments in registers (B-operand of S^T GEMM)
  v8s qF[2][2];
  #pragma unroll
  for (int ci = 0; ci < 2; ci++)
    #pragma unroll
    for (int ks = 0; ks < 2; ks++)
      qF[ci][ks] = *(const v8s*)(qT + ((bh * Ll) + l0 + w * 32 + ci * 16 + lid) * 64 + ks * 32 + quad * 8);

  const v8s onesF = {0x3F80, 0x3F80, 0x3F80, 0x3F80, 0x3F80, 0x3F80, 0x3F80, 0x3F80};
  v4f o[2][4] = {};                // [ci][df]
  v4f o1[2] = {};                  // lsum accumulators (all cols equal)

  // prologue: stage mt=0; drain Q-loads + K(0) (oldest 8), leave V(0) in flight
  STAGE_KV(0);
  asm volatile("s_waitcnt vmcnt(4)" ::: "memory");
  __builtin_amdgcn_sched_barrier(0);
  __builtin_amdgcn_s_barrier();

  for (int mt = 0; mt < 16; mt++){
    if (mt < 15) STAGE_KV(mt + 1);              // 8 DMAs; V(mt) 4 still in flight
    const u16* kcur = &kls[mt & 1][0];
    const u16* vcur = &vls[mt & 1][0];

    // S^T: s[c][tt][ci] reg r = S^T[m0 + c*32 + quad*8 + tt*4 + r][w*32+ci*16+lid]
    v4f s[4][2][2] = {};
    #pragma unroll
    for (int ks = 0; ks < 2; ks++){
      v8s aF[4][2];
      #pragma unroll
      for (int c = 0; c < 4; c++)
        #pragma unroll
        for (int tt = 0; tt < 2; tt++)
          aF[c][tt] = *(const v8s*)&kcur[(c * 32 + tt * 16 + lid) * 64 + ((ks * 32 + quad * 8) ^ xk)];
      __builtin_amdgcn_s_setprio(1);
      #pragma unroll
      for (int c = 0; c < 4; c++)
        #pragma unroll
        for (int tt = 0; tt < 2; tt++){
          s[c][tt][0] = __builtin_amdgcn_mfma_f32_16x16x32_bf16(aF[c][tt], qF[0][ks], s[c][tt][0], 0, 0, 0);
          s[c][tt][1] = __builtin_amdgcn_mfma_f32_16x16x32_bf16(aF[c][tt], qF[1][ks], s[c][tt][1], 0, 0, 0);
        }
      __builtin_amdgcn_s_setprio(0);
    }

    // V(mt) certified for all waves: own-wave counted wait + barrier
    if (mt < 15){
      asm volatile("s_waitcnt vmcnt(8)" ::: "memory");   // V(mt) landed; K/V(mt+1) in flight
    } else {
      asm volatile("s_waitcnt vmcnt(0)" ::: "memory");
    }
    __builtin_amdgcn_sched_barrier(0);
    __builtin_amdgcn_s_barrier();

    // fixed-max softmax: p = exp2(s) packed straight into PV A-frags; lsum via ones-MFMA
    #pragma unroll
    for (int c = 0; c < 4; c++){
      v8s aP[2];
      #pragma unroll
      for (int ci = 0; ci < 2; ci++){
        float p[8];
        #pragma unroll
        for (int tt = 0; tt < 2; tt++)
          #pragma unroll
          for (int r = 0; r < 4; r++)
            p[tt * 4 + r] = EXP2F(s[c][tt][ci][r]);
        unsigned u[4];
        #pragma unroll
        for (int k2 = 0; k2 < 4; k2++){
          __hip_bfloat162 hb = __float22bfloat162_rn(make_float2(p[2 * k2], p[2 * k2 + 1]));
          __builtin_memcpy(&u[k2], &hb, 4);
        }
        __builtin_memcpy(&aP[ci], u, 16);
      }
      v8s bV[4];
      #pragma unroll
      for (int df = 0; df < 4; df++)
        bV[df] = *(const v8s*)&vcur[(df * 16 + lid) * 128 + ((c * 32 + quad * 8) ^ xk)];
      __builtin_amdgcn_s_setprio(1);
      #pragma unroll
      for (int ci = 0; ci < 2; ci++){
        #pragma unroll
        for (int df = 0; df < 4; df++)
          o[ci][df] = __builtin_amdgcn_mfma_f32_16x16x32_bf16(aP[ci], bV[df], o[ci][df], 0, 0, 0);
        o1[ci] = __builtin_amdgcn_mfma_f32_16x16x32_bf16(aP[ci], onesF, o1[ci], 0, 0, 0);
      }
      __builtin_amdgcn_s_setprio(0);
    }

    // end of phase: certify K(mt+1) (own-wave) before barrier; V(mt+1) stays in flight
    if (mt < 15){
      asm volatile("s_waitcnt vmcnt(4)" ::: "memory");
      __builtin_amdgcn_sched_barrier(0);
      __builtin_amdgcn_s_barrier();
    }
  }
#undef STAGE_KV

  #pragma unroll
  for (int lf = 0; lf < 2; lf++){
    v4f nv;
    #pragma unroll
    for (int r = 0; r < 4; r++) nv[r] = 1.f / o1[lf][r];
    #pragma unroll
    for (int df = 0; df < 4; df++){
      int d = df * 16 + lid;
      int l = l0 + w * 32 + lf * 16 + quad * 4;
      size_t ofs = (((bh << 6) + d) << 11) + l;
      if (isf32){
        v4f st;
        #pragma unroll
        for (int r = 0; r < 4; r++) st[r] = o[lf][df][r] * nv[r];
        *(v4f*)((float*)outv + ofs) = st;
      } else {
        u16x4 pk;
        #pragma unroll
        for (int r = 0; r < 4; r++) pk[r] = f2bf(o[lf][df][r] * nv[r]);
        *(u16x4*)((u16*)outv + ofs) = pk;
      }
    }
  }
}

extern "C" void kernel_launch(void* const* d_in, const int* in_sizes, int n_in,
                              void* d_out, int out_size, void* d_ws, size_t ws_size,
                              hipStream_t stream){
  const void* x  = d_in[0];
  const void* w0 = d_in[1];
  const void* b0 = d_in[2];
  const void* w1 = d_in[3];
  const void* b1 = d_in[4];
  const void* w2 = d_in[5];
  const void* b2 = d_in[6];
  u16* ws = (u16*)d_ws;
  unsigned* flag = (unsigned*)ws;                // 1 u32 at base (64 u16 slot, aligned)
  u16* xT = ws + 64;                             // [8][2050][512]
  u16* wp = xT + (size_t)8 * 2050 * 512;         // [9][512][512]
  u16* bb = wp + (size_t)9 * 512 * 512;          // [3][512]
  u16* qT = bb + 1536;                           // [8][8][2048][64]
  u16* kT = qT + (size_t)8 * 8 * 2048 * 64;
  u16* vN = kT + (size_t)8 * 8 * 2048 * 64;      // [8][512][2048]

  detect_dtype<<<1, 256, 0, stream>>>((const u16*)x, flag);
  transpose_pad<<<dim3(32, 8, 8), 256, 0, stream>>>(x, flag, xT);
  pack_wb<<<dim3(9 * 512 * 512 / 256 + 6), 256, 0, stream>>>(w0, w1, w2, b0, b1, b2, flag, wp, bb);
  conv_gemm_fused<<<dim3(768), 512, 0, stream>>>(wp, xT, bb, qT, kT, vN);
  attn_kernel<<<dim3(64, 16), 256, 0, stream>>>(qT, kT, vN, flag, d_out);
}